// Round 2
// baseline (8438.642 us; speedup 1.0000x reference)
//
#include <hip/hip_runtime.h>
#include <hip/hip_bf16.h>

// ClippedGRU: B=256, T=500, I=128, H=512, clip ±5. fp32 in/out, bf16 MFMA core.
//
// Persistent cooperative kernel. Grid = 256 blocks = 16 batch-groups (16 rows,
// = MFMA M) x 16 unit-strips (32 h-units -> 96 rows of W_hh/W_ih).
// W_hh strip (96x512) and W_ih strip (96x128) are converted fp32->bf16 once
// and live in REGISTERS as MFMA B-fragments across the block's 6 GEMM waves
// (wave = gate x half-strip of 16 units). Per step: fused ih-GEMM (overlaps
// the flag spin), hh-GEMM from register W, gate math in fp32 via LDS, publish
// bf16 h-strip to a double-buffered global h, fp32 h to out, per-block release
// byte-flag; group peers acquire-poll their 16 flags (one 16B line).
// One wait per step suffices: flags[t-1]==all implies all peers consumed
// h buffer ((t+1)&1)'s previous contents, so overwriting it at step t is safe.

#define T_STEPS 500
#define B_TOT   256
#define I_DIM   128
#define H_DIM   512
#define BB      16      // batch rows per group (= MFMA M)
#define UU      32      // h-units per block strip
#define TPAD    512     // padded T for flag indexing
#define FLAGS_BYTES (16 * TPAD * 16)   // [group][t][block] bytes = 128 KB

typedef __bf16 bf16x8 __attribute__((ext_vector_type(8)));
typedef float  f32x4  __attribute__((ext_vector_type(4)));
typedef float  f32x8  __attribute__((ext_vector_type(8)));

__device__ __forceinline__ bf16x8 cvt8(const float* p) {
    f32x8 v = *(const f32x8*)p;   // 32B load (2x dwordx4)
    bf16x8 r;
#pragma unroll
    for (int i = 0; i < 8; ++i) r[i] = (__bf16)v[i];   // RNE cvt
    return r;
}

__device__ __forceinline__ float fast_sigmoid(float x) {
    float e = __builtin_amdgcn_exp2f(-1.4426950408889634f * x);
    return __builtin_amdgcn_rcpf(1.0f + e);
}
__device__ __forceinline__ float fast_tanh(float x) {
    // tanh(x) = 1 - 2/(exp(2x)+1); saturates correctly for |x| large.
    float e = __builtin_amdgcn_exp2f(2.8853900817779268f * x);
    return 1.0f - 2.0f * __builtin_amdgcn_rcpf(1.0f + e);
}

__global__ __launch_bounds__(512, 2)
void gru_persist(const float* __restrict__ x,
                 const float* __restrict__ h0,
                 const float* __restrict__ wih,
                 const float* __restrict__ whh,
                 const float* __restrict__ bih,
                 const float* __restrict__ bhh,
                 float* __restrict__ out,
                 unsigned char* __restrict__ flags,   // [16][TPAD][16], zeroed
                 __hip_bfloat16* __restrict__ hbuf)   // [2][256][512] bf16
{
    const int tid  = threadIdx.x;
    const int bx   = blockIdx.x;
    const int g    = bx >> 4;          // batch group 0..15
    const int j    = bx & 15;          // unit strip 0..15
    const int bg   = g * BB;           // batch base
    const int u0   = j * UU;           // unit base
    const int w    = tid >> 6;         // wave 0..7 (0-5 GEMM, 6 spinner, 7 idle)
    const int lane = tid & 63;
    const int lrow = lane & 15;        // MFMA m / n index within fragment
    const int lq   = lane >> 4;        // quad 0..3

    __shared__ float s_r [16 * 33];    // xi_r + hh_r (padded stride 33)
    __shared__ float s_z [16 * 33];
    __shared__ float s_hn[16 * 33];    // hh_n only
    __shared__ float s_xn[16 * 33];    // xi_n only
    __shared__ float s_hold[16 * 32];  // fp32 carried h strip (never rounded)
    __shared__ float s_bih[3 * 32];
    __shared__ float s_bhh[3 * 32];

    // ---- one-time init: local h strip (fp32) + bias strips ----
    {
        int b = tid >> 5, u = tid & 31;
        s_hold[b * 32 + u] = h0[(size_t)(bg + b) * H_DIM + u0 + u];
        if (tid < 96) {
            int gg = tid >> 5, uu = tid & 31;
            s_bih[tid] = bih[gg * H_DIM + u0 + uu];
            s_bhh[tid] = bhh[gg * H_DIM + u0 + uu];
        }
    }

    // ---- one-time: W_hh / W_ih strips -> bf16 register B-fragments ----
    // wave w: gate = w>>1 (0=r,1=z,2=n), hf = w&1 (which 16 of the 32 units)
    const int gate = w >> 1;
    const int hf   = w & 1;
    bf16x8 wf[16], wfi[4];
    if (w < 6) {
        const long row0 = (long)gate * H_DIM + u0 + 16 * hf;  // row in [0,1536)
        const float* wr  = whh + (row0 + lrow) * H_DIM + lq * 8;
        const float* wr2 = wih + (row0 + lrow) * I_DIM + lq * 8;
#pragma unroll
        for (int kt = 0; kt < 16; ++kt) wf[kt] = cvt8(wr + kt * 32);
#pragma unroll
        for (int kt = 0; kt < 4; ++kt)  wfi[kt] = cvt8(wr2 + kt * 32);
    }
    __syncthreads();

    int sync_ok = 1;  // spinner-private timeout latch (fail-fast, no hang)

    for (int t = 0; t < T_STEPS; ++t) {
        f32x4 accA = {0, 0, 0, 0}, accB = {0, 0, 0, 0}, accX = {0, 0, 0, 0};

        // ---- ih GEMM for step t (independent of h -> overlaps the spin) ----
        if (w < 6) {
            const float* xr =
                x + ((size_t)(bg + lrow) * T_STEPS + t) * I_DIM + lq * 8;
            bf16x8 xf0 = cvt8(xr);
            bf16x8 xf1 = cvt8(xr + 32);
            bf16x8 xf2 = cvt8(xr + 64);
            bf16x8 xf3 = cvt8(xr + 96);
            f32x4 ai = {0, 0, 0, 0};
            ai = __builtin_amdgcn_mfma_f32_16x16x32_bf16(xf0, wfi[0], ai, 0, 0, 0);
            ai = __builtin_amdgcn_mfma_f32_16x16x32_bf16(xf1, wfi[1], ai, 0, 0, 0);
            ai = __builtin_amdgcn_mfma_f32_16x16x32_bf16(xf2, wfi[2], ai, 0, 0, 0);
            ai = __builtin_amdgcn_mfma_f32_16x16x32_bf16(xf3, wfi[3], ai, 0, 0, 0);
            if (gate < 2) accA = ai; else accX = ai;
        }

        // ---- wait for h_t publication by all 16 group peers (end of t-1) ----
        if (w == 6 && lane == 0 && t > 0) {
            const unsigned long long* fl = (const unsigned long long*)
                (flags + ((size_t)g * TPAD + (t - 1)) * 16);
            if (sync_ok) {
                long tries = 0;
                for (;;) {
                    unsigned long long a = __hip_atomic_load(
                        fl, __ATOMIC_RELAXED, __HIP_MEMORY_SCOPE_AGENT);
                    unsigned long long b = __hip_atomic_load(
                        fl + 1, __ATOMIC_RELAXED, __HIP_MEMORY_SCOPE_AGENT);
                    if (a == 0x0101010101010101ull &&
                        b == 0x0101010101010101ull) break;
                    __builtin_amdgcn_s_sleep(2);
                    if (++tries > (1L << 20)) { sync_ok = 0; break; }
                }
            }
            __threadfence();   // acquire: inv L1 + XCD-L2 before h reads
        }
        __syncthreads();

        // ---- hh GEMM: A = h_t fragments (global bf16), B = register W ----
        if (w < 6) {
            bf16x8 hfr[16];
            if (t == 0) {
                const float* hr0 = h0 + (size_t)(bg + lrow) * H_DIM + lq * 8;
#pragma unroll
                for (int kt = 0; kt < 16; ++kt) hfr[kt] = cvt8(hr0 + kt * 32);
            } else {
                const __hip_bfloat16* hr =
                    hbuf + (size_t)(t & 1) * B_TOT * H_DIM +
                    (size_t)(bg + lrow) * H_DIM + lq * 8;
#pragma unroll
                for (int kt = 0; kt < 16; ++kt)
                    hfr[kt] = *(const bf16x8*)(hr + kt * 32);
            }
#pragma unroll
            for (int kt = 0; kt < 8; ++kt)
                accA = __builtin_amdgcn_mfma_f32_16x16x32_bf16(hfr[kt], wf[kt],
                                                               accA, 0, 0, 0);
#pragma unroll
            for (int kt = 8; kt < 16; ++kt)
                accB = __builtin_amdgcn_mfma_f32_16x16x32_bf16(hfr[kt], wf[kt],
                                                               accB, 0, 0, 0);
            // C layout: col = lane&15 (unit), row = (lane>>4)*4+i (batch)
            float* dst = (gate == 0) ? s_r : (gate == 1 ? s_z : s_hn);
            const int col = hf * 16 + lrow;
#pragma unroll
            for (int i = 0; i < 4; ++i) {
                int b = lq * 4 + i;
                dst[b * 33 + col] = accA[i] + accB[i];
                if (gate == 2) s_xn[b * 33 + col] = accX[i];
            }
        }
        __syncthreads();

        // ---- gate math (fp32), 512 threads = 16 batches x 32 units ----
        {
            int b = tid >> 5, u = tid & 31;
            float rr = fast_sigmoid(s_r[b * 33 + u] + s_bih[u] + s_bhh[u]);
            float zz = fast_sigmoid(s_z[b * 33 + u] + s_bih[32 + u] + s_bhh[32 + u]);
            float nn = fast_tanh(s_xn[b * 33 + u] + s_bih[64 + u] +
                                 rr * (s_hn[b * 33 + u] + s_bhh[64 + u]));
            float hprev = s_hold[b * 32 + u];
            float hnew  = (1.0f - zz) * nn + zz * hprev;
            hnew = fminf(fmaxf(hnew, -5.0f), 5.0f);
            s_hold[b * 32 + u] = hnew;
            out[((size_t)(bg + b) * T_STEPS + t) * H_DIM + u0 + u] = hnew;
            hbuf[(size_t)((t + 1) & 1) * B_TOT * H_DIM +
                 (size_t)(bg + b) * H_DIM + u0 + u] = __float2bfloat16(hnew);
            if (t == T_STEPS - 1)
                out[(size_t)B_TOT * T_STEPS * H_DIM +
                    (size_t)(bg + b) * H_DIM + u0 + u] = hnew;
        }
        __syncthreads();   // vmcnt drained: strip stores at least in L2

        // ---- publish: agent release store (wbl2) then flag byte ----
        if (tid == 0 && t < T_STEPS - 1) {
            __hip_atomic_store(flags + ((size_t)g * TPAD + t) * 16 + j,
                               (unsigned char)1, __ATOMIC_RELEASE,
                               __HIP_MEMORY_SCOPE_AGENT);
        }
    }
}

extern "C" void kernel_launch(void* const* d_in, const int* in_sizes, int n_in,
                              void* d_out, int out_size, void* d_ws, size_t ws_size,
                              hipStream_t stream) {
    const float* x   = (const float*)d_in[0];
    const float* h0  = (const float*)d_in[1];
    const float* wih = (const float*)d_in[2];
    const float* whh = (const float*)d_in[3];
    const float* bih = (const float*)d_in[4];
    const float* bhh = (const float*)d_in[5];
    float* out = (float*)d_out;
    unsigned char*  flags = (unsigned char*)d_ws;
    __hip_bfloat16* hbuf  = (__hip_bfloat16*)((char*)d_ws + FLAGS_BYTES);

    // flags must start at 0 every launch (ws is re-poisoned to 0xAA).
    hipMemsetAsync(d_ws, 0, FLAGS_BYTES, stream);

    void* args[] = { (void*)&x, (void*)&h0, (void*)&wih, (void*)&whh,
                     (void*)&bih, (void*)&bhh, (void*)&out,
                     (void*)&flags, (void*)&hbuf };
    // Cooperative launch guarantees all 256 blocks (1/CU) are co-resident,
    // which the group-local spin barriers require.
    hipLaunchCooperativeKernel((void*)gru_persist, dim3(256), dim3(512),
                               args, 0, stream);
}